// Round 16
// baseline (142.971 us; speedup 1.0000x reference)
//
#include <hip/hip_runtime.h>

typedef _Float16 half_t;
typedef _Float16 h2 __attribute__((ext_vector_type(2)));
typedef unsigned int uint32;

#define K_ 100
#define F_ 128
#define E_ 200

#if defined(__has_builtin)
#if __has_builtin(__builtin_amdgcn_fdot2)
#define FDOT2(a,b,c) __builtin_amdgcn_fdot2((a),(b),(c),false)
#endif
#endif
#ifndef FDOT2
#define FDOT2(a,b,c) fmaf((float)(a).y,(float)(b).y, fmaf((float)(a).x,(float)(b).x,(c)))
#endif

__device__ __forceinline__ h2 bch2(uint32 u){ return __builtin_bit_cast(h2,u); }
__device__ __forceinline__ uint32 pkh2(float a, float b){
  h2 p; p.x=(half_t)a; p.y=(half_t)b; return __builtin_bit_cast(uint32,p);
}

// ws layout (uints): Lh[6400][100] @0 ; Rh[6400][100] @640000 ; ah2[100] @1280000
#define LH_OFF 0
#define RH_OFF 640000
#define AH_OFF 1280000

// K1 v3: NO W staging, NO transposes, NO mid-loop barriers.
// thread = W column e (coalesced W loads -> 32 regs/chunk); x via wave-uniform
// addresses -> scalar s_load + v_fmac (SGPR operand). f32 accumulation.
// 10 rows/block, grid 640. LDS only for the final h2-pack.
__global__ __launch_bounds__(256) void k_proj(
    const float* __restrict__ x, const float* __restrict__ W,
    const float* __restrict__ bvec, const float* __restrict__ avec,
    uint32* __restrict__ ws)
{
  const int t  = threadIdx.x;
  const int r0 = (int)blockIdx.x * 10;

  __shared__ float ls[4000];    // [0..1999]=L [r][e], [2000..3999]=R [r][e]  16 KB

  if (blockIdx.x == 0 && t < 100)
    ws[AH_OFF + t] = pkh2(avec[2*t], avec[2*t+1]);

  if (t < 200) {
    float accL[10], accR[10];
    #pragma unroll
    for (int r = 0; r < 10; ++r) { accL[r] = 0.f; accR[r] = 0.f; }
    const float* Wc = W + t;                  // column e = t
    #pragma unroll
    for (int fc = 0; fc < 8; ++fc) {          // W rows fc*32..+31 (0..255)
      float wr[32];
      #pragma unroll
      for (int k = 0; k < 32; ++k)
        wr[k] = Wc[(size_t)(fc*32 + k) * E_];
      #pragma unroll
      for (int r = 0; r < 10; ++r) {
        const float* xr = x + (size_t)(r0 + r) * F_ + (fc & 3) * 32;  // uniform -> s_load
        if (fc < 4) {
          #pragma unroll
          for (int k = 0; k < 32; ++k) accL[r] = fmaf(xr[k], wr[k], accL[r]);
        } else {
          #pragma unroll
          for (int k = 0; k < 32; ++k) accR[r] = fmaf(xr[k], wr[k], accR[r]);
        }
      }
    }
    float bv = bvec[t];
    #pragma unroll
    for (int r = 0; r < 10; ++r) {
      ls[r * 200 + t]        = accL[r];
      ls[2000 + r * 200 + t] = accR[r] + bv;
    }
  }
  __syncthreads();

  // pack f32 pairs -> h2 uints, coalesced stores to ws
  for (int u = t; u < 2000; u += 256) {
    int side = u / 1000, rem = u - side * 1000;
    int r = rem / 100, e2 = rem - r * 100;
    const float* src = ls + side * 2000 + r * 200 + 2 * e2;
    uint32 val = pkh2(src[0], src[1]);
    ws[(side ? RH_OFF : LH_OFF) + (size_t)(r0 + r) * 100 + e2] = val;
  }
}

// one e-uint (2 e's) of the pair sweep + aL/aR side-dots
#define STEP(lu, au, r0u, r1u, r2u, r3u)                                   \
  do {                                                                     \
    h2 a2 = bch2(au); h2 l2 = bch2(lu); h2 rr, mm;                         \
    al = FDOT2(a2, l2, al);                                                \
    rr = bch2(r0u); ar[0] = FDOT2(a2, rr, ar[0]);                          \
    mm = __builtin_elementwise_min(l2 + rr, z2); acc[0] = FDOT2(a2, mm, acc[0]); \
    rr = bch2(r1u); ar[1] = FDOT2(a2, rr, ar[1]);                          \
    mm = __builtin_elementwise_min(l2 + rr, z2); acc[1] = FDOT2(a2, mm, acc[1]); \
    rr = bch2(r2u); ar[2] = FDOT2(a2, rr, ar[2]);                          \
    mm = __builtin_elementwise_min(l2 + rr, z2); acc[2] = FDOT2(a2, mm, acc[2]); \
    rr = bch2(r3u); ar[3] = FDOT2(a2, rr, ar[3]);                          \
    mm = __builtin_elementwise_min(l2 + rr, z2); acc[3] = FDOT2(a2, mm, acc[3]); \
  } while (0)

// K2 v2: 10-row i-tiles -> grid (10,64)=640 blocks x 256 thr (2.5 blocks/CU).
// Sweep reads L/R h2 from global into regs; softmax; h2 epilogue.
__global__ __launch_bounds__(256) void k_main(
    const float* __restrict__ x, const float* __restrict__ bias,
    const uint32* __restrict__ ws, float* __restrict__ out)
{
  const int t  = threadIdx.x;
  const int i0 = (int)blockIdx.x * 10;
  const int b  = (int)blockIdx.y;

  __shared__ float  att[1000];     // 4 KB
  __shared__ uint32 att2[500];     // 2 KB
  __shared__ float  scratch[256];
  __shared__ float  rowmax[10], rowinv[10];

  const bool act = (t < 250);
  const int ti = act ? (t % 10) : 0;      // i = i0 + ti
  const int tj = act ? (t / 10) : 0;      // j = tj + 25s, tj 0..24

  const uint32* Lrow = ws + LH_OFF + (size_t)(b*K_ + i0 + ti) * 100;
  const uint32* R0   = ws + RH_OFF + (size_t)(b*K_ + tj) * 100;
  const uint32* Ap   = ws + AH_OFF;

  float acc[4] = {0.f,0.f,0.f,0.f};
  float ar[4]  = {0.f,0.f,0.f,0.f};
  float al = 0.f;
  h2 z2; z2.x = (half_t)0; z2.y = (half_t)0;

  #pragma unroll
  for (int g = 0; g < 12; ++g) {
    const int ba = 8*g;
    uint4 La = *(const uint4*)(Lrow + ba),      Lb = *(const uint4*)(Lrow + ba + 4);
    uint4 Aa = *(const uint4*)(Ap + ba),        Ab = *(const uint4*)(Ap + ba + 4);
    uint4 R0a = *(const uint4*)(R0 + ba),       R0b = *(const uint4*)(R0 + ba + 4);
    uint4 R1a = *(const uint4*)(R0 + 2500+ba),  R1b = *(const uint4*)(R0 + 2500+ba+4);
    uint4 R2a = *(const uint4*)(R0 + 5000+ba),  R2b = *(const uint4*)(R0 + 5000+ba+4);
    uint4 R3a = *(const uint4*)(R0 + 7500+ba),  R3b = *(const uint4*)(R0 + 7500+ba+4);
    STEP(La.x, Aa.x, R0a.x, R1a.x, R2a.x, R3a.x);
    STEP(La.y, Aa.y, R0a.y, R1a.y, R2a.y, R3a.y);
    STEP(La.z, Aa.z, R0a.z, R1a.z, R2a.z, R3a.z);
    STEP(La.w, Aa.w, R0a.w, R1a.w, R2a.w, R3a.w);
    STEP(Lb.x, Ab.x, R0b.x, R1b.x, R2b.x, R3b.x);
    STEP(Lb.y, Ab.y, R0b.y, R1b.y, R2b.y, R3b.y);
    STEP(Lb.z, Ab.z, R0b.z, R1b.z, R2b.z, R3b.z);
    STEP(Lb.w, Ab.w, R0b.w, R1b.w, R2b.w, R3b.w);
  }
  {
    uint4 La = *(const uint4*)(Lrow + 96);
    uint4 Aa = *(const uint4*)(Ap + 96);
    uint4 R0a = *(const uint4*)(R0 + 96);
    uint4 R1a = *(const uint4*)(R0 + 2596);
    uint4 R2a = *(const uint4*)(R0 + 5096);
    uint4 R3a = *(const uint4*)(R0 + 7596);
    STEP(La.x, Aa.x, R0a.x, R1a.x, R2a.x, R3a.x);
    STEP(La.y, Aa.y, R0a.y, R1a.y, R2a.y, R3a.y);
    STEP(La.z, Aa.z, R0a.z, R1a.z, R2a.z, R3a.z);
    STEP(La.w, Aa.w, R0a.w, R1a.w, R2a.w, R3a.w);
  }

  float v[4];
  if (act) {
    #pragma unroll
    for (int s = 0; s < 4; ++s) {
      int j = tj + 25*s;
      float lv = al + ar[s] + bias[(i0 + ti)*K_ + j] - 0.8f*acc[s];
      v[s] = fminf(fmaxf(lv, -30000.f), 30000.f);
    }
  }

  // softmax over j: row ti's 25 partials live at threads t = ti + 10k
  {
    float m = -3.0e38f;
    if (act) {
      #pragma unroll
      for (int s = 0; s < 4; ++s) m = fmaxf(m, v[s]);
    }
    scratch[t] = m;
    __syncthreads();
    if (t < 10) {
      float mm = scratch[t];
      for (int k = 1; k < 25; ++k) mm = fmaxf(mm, scratch[t + 10*k]);
      rowmax[t] = mm;
    }
    __syncthreads();
    float ssum = 0.f;
    if (act) {
      float m2 = rowmax[ti];
      #pragma unroll
      for (int s = 0; s < 4; ++s) ssum += __expf(v[s] - m2);
    }
    scratch[t] = ssum;
    __syncthreads();
    if (t < 10) {
      float s2 = 0.f;
      for (int k = 0; k < 25; ++k) s2 += scratch[t + 10*k];
      rowinv[t] = 1.f / s2;
    }
    __syncthreads();
  }
  if (act) {
    float m = rowmax[ti], inv = rowinv[ti];
    #pragma unroll
    for (int s = 0; s < 4; ++s)
      att[ti*K_ + tj + 25*s] = __expf(v[s] - m) * inv;
  }
  __syncthreads();
  for (int u = t; u < 500; u += 256) {
    int i = u / 50, jp = u - i*50;
    att2[i*50 + jp] = pkh2(att[i*K_ + 2*jp], att[i*K_ + 2*jp + 1]);
  }
  __syncthreads();

  // epilogue: h = sigmoid(att @ x); rows ig+2m (5 per thread), f coalesced.
  {
    const int f = t & 127, ig = t >> 7;     // ig 0..1
    float z[5];
    #pragma unroll
    for (int m = 0; m < 5; ++m) z[m] = 0.f;
    const float* xb = x + (size_t)b*K_*F_ + f;
    for (int jp = 0; jp < 50; ++jp) {
      float x0 = xb[(size_t)(2*jp)*F_];
      float x1 = xb[(size_t)(2*jp+1)*F_];
      h2 xv = bch2(pkh2(x0, x1));
      #pragma unroll
      for (int m = 0; m < 5; ++m) {
        h2 av = bch2(att2[(ig + 2*m)*50 + jp]);
        z[m] = FDOT2(av, xv, z[m]);
      }
    }
    #pragma unroll
    for (int m = 0; m < 5; ++m) {
      int i = ig + 2*m;
      out[(size_t)(b*K_ + i0 + i)*F_ + f] = 1.f / (1.f + __expf(-z[m]));
    }
  }
}

extern "C" void kernel_launch(void* const* d_in, const int* in_sizes, int n_in,
                              void* d_out, int out_size, void* d_ws, size_t ws_size,
                              hipStream_t stream)
{
  const float* x    = (const float*)d_in[0];   // (64,100,128) f32
  const float* W    = (const float*)d_in[1];   // (256,200) f32
  const float* bvec = (const float*)d_in[2];   // (200,) f32
  const float* avec = (const float*)d_in[3];   // (200,) f32
  const float* bias = (const float*)d_in[4];   // (100,100) f32
  float* out  = (float*)d_out;                 // (64,100,128) f32
  uint32* ws  = (uint32*)d_ws;                 // 5.12 MB used

  k_proj<<<dim3(640), dim3(256), 0, stream>>>(x, W, bvec, avec, ws);
  k_main<<<dim3(10, 64), dim3(256), 0, stream>>>(x, bias, ws, out);
}

// Round 17
// 102.334 us; speedup vs baseline: 1.3971x; 1.3971x over previous
//
#include <hip/hip_runtime.h>

typedef _Float16 half_t;
typedef _Float16 h2 __attribute__((ext_vector_type(2)));
typedef unsigned int uint32;

#define K_ 100
#define F_ 128
#define E_ 200

#if defined(__has_builtin)
#if __has_builtin(__builtin_amdgcn_fdot2)
#define FDOT2(a,b,c) __builtin_amdgcn_fdot2((a),(b),(c),false)
#endif
#endif
#ifndef FDOT2
#define FDOT2(a,b,c) fmaf((float)(a).y,(float)(b).y, fmaf((float)(a).x,(float)(b).x,(c)))
#endif

__device__ __forceinline__ h2 bch2(uint32 u){ return __builtin_bit_cast(h2,u); }
__device__ __forceinline__ uint32 pkh2(float a, float b){
  h2 p; p.x=(half_t)a; p.y=(half_t)b; return __builtin_bit_cast(uint32,p);
}

// ws layout (uints): Lh[6400][100] @0 ; Rh[6400][100] @640000 ; ah2[100] @1280000 ;
// WT[400][64] @1280128 (h2 f-pairs per unified e-column; cu<200 = W1/L, >=200 = W2/R)
#define LH_OFF 0
#define RH_OFF 640000
#define AH_OFF 1280000
#define WT_OFF 1280128

// K0: one-time W transpose -> fp16 f-pair columns in ws. grid 25 x 256.
// Block: 8 e-values, both halves of W (16 output columns).
__global__ __launch_bounds__(256) void k_wt(
    const float* __restrict__ W, const float* __restrict__ avec,
    uint32* __restrict__ ws)
{
  const int t  = threadIdx.x;
  const int e0 = (int)blockIdx.x * 8;
  __shared__ float wtf[256 * 9];     // [f][ec], pad 9 vs bank conflicts  9.2 KB

  for (int u = t; u < 2048; u += 256) {
    int f = u >> 3, ec = u & 7;
    wtf[f * 9 + ec] = W[(size_t)f * E_ + e0 + ec];
  }
  if (blockIdx.x == 0 && t < 100)
    ws[AH_OFF + t] = pkh2(avec[2*t], avec[2*t+1]);
  __syncthreads();

  for (int u = t; u < 1024; u += 256) {
    int col16 = u >> 6, f2 = u & 63;
    int side = col16 >> 3, el = col16 & 7;
    int cu = side * 200 + e0 + el;
    int fbase = side * 128;
    ws[WT_OFF + (size_t)cu * 64 + f2] =
        pkh2(wtf[(fbase + 2*f2) * 9 + el], wtf[(fbase + 2*f2 + 1) * 9 + el]);
  }
}

// K1 v4: thread t owns unified e-column pair (2t, 2t+1). WT cols read with 16
// uint4 loads each (L2-hot); x staged once in LDS (broadcast reads). 1280
// fdot2/thread, f32 accum, h2 stores in final layout. 10 rows/block, grid 640.
__global__ __launch_bounds__(256) void k_proj(
    const float* __restrict__ x, const float* __restrict__ bvec,
    uint32* __restrict__ ws)
{
  const int t  = threadIdx.x;
  const int r0 = (int)blockIdx.x * 10;

  __shared__ __align__(16) uint32 xsh[10 * 64];   // x rows, h2 f-pairs  2.6 KB

  for (int u = t; u < 640; u += 256) {
    int row = u >> 6, f2 = u & 63;
    const float* xp = x + (size_t)(r0 + row) * F_ + 2 * f2;
    xsh[row * 64 + f2] = pkh2(xp[0], xp[1]);
  }
  __syncthreads();

  if (t < 200) {
    const uint32* wt0 = ws + WT_OFF + (size_t)(2 * t) * 64;
    const uint32* wt1 = wt0 + 64;
    float acc0[10], acc1[10];
    #pragma unroll
    for (int r = 0; r < 10; ++r) { acc0[r] = 0.f; acc1[r] = 0.f; }
    #pragma unroll
    for (int q = 0; q < 16; ++q) {
      uint4 w0 = *(const uint4*)(wt0 + 4 * q);
      uint4 w1 = *(const uint4*)(wt1 + 4 * q);
      #pragma unroll
      for (int r = 0; r < 10; ++r) {
        uint4 xq = *(const uint4*)(xsh + r * 64 + 4 * q);   // uniform -> broadcast
        acc0[r] = FDOT2(bch2(xq.x), bch2(w0.x), acc0[r]);
        acc0[r] = FDOT2(bch2(xq.y), bch2(w0.y), acc0[r]);
        acc0[r] = FDOT2(bch2(xq.z), bch2(w0.z), acc0[r]);
        acc0[r] = FDOT2(bch2(xq.w), bch2(w0.w), acc0[r]);
        acc1[r] = FDOT2(bch2(xq.x), bch2(w1.x), acc1[r]);
        acc1[r] = FDOT2(bch2(xq.y), bch2(w1.y), acc1[r]);
        acc1[r] = FDOT2(bch2(xq.z), bch2(w1.z), acc1[r]);
        acc1[r] = FDOT2(bch2(xq.w), bch2(w1.w), acc1[r]);
      }
    }
    const bool isR = (t >= 100);
    const int e2 = isR ? (t - 100) : t;    // output uint index within row
    if (isR) {
      float b0 = bvec[2 * e2], b1 = bvec[2 * e2 + 1];
      #pragma unroll
      for (int r = 0; r < 10; ++r) { acc0[r] += b0; acc1[r] += b1; }
    }
    uint32* dst = ws + (isR ? RH_OFF : LH_OFF);
    #pragma unroll
    for (int r = 0; r < 10; ++r)
      dst[(size_t)(r0 + r) * 100 + e2] = pkh2(acc0[r], acc1[r]);
  }
}

// one e-uint (2 e's) of the pair sweep + aL/aR side-dots
#define STEP(lu, au, r0u, r1u, r2u, r3u)                                   \
  do {                                                                     \
    h2 a2 = bch2(au); h2 l2 = bch2(lu); h2 rr, mm;                         \
    al = FDOT2(a2, l2, al);                                                \
    rr = bch2(r0u); ar[0] = FDOT2(a2, rr, ar[0]);                          \
    mm = __builtin_elementwise_min(l2 + rr, z2); acc[0] = FDOT2(a2, mm, acc[0]); \
    rr = bch2(r1u); ar[1] = FDOT2(a2, rr, ar[1]);                          \
    mm = __builtin_elementwise_min(l2 + rr, z2); acc[1] = FDOT2(a2, mm, acc[1]); \
    rr = bch2(r2u); ar[2] = FDOT2(a2, rr, ar[2]);                          \
    mm = __builtin_elementwise_min(l2 + rr, z2); acc[2] = FDOT2(a2, mm, acc[2]); \
    rr = bch2(r3u); ar[3] = FDOT2(a2, rr, ar[3]);                          \
    mm = __builtin_elementwise_min(l2 + rr, z2); acc[3] = FDOT2(a2, mm, acc[3]); \
  } while (0)

// K2: EXACT R15-measured version (640 thr, grid (4,64)) — clean control.
__global__ __launch_bounds__(640) void k_main(
    const float* __restrict__ x, const float* __restrict__ bias,
    const uint32* __restrict__ ws, float* __restrict__ out)
{
  const int t  = threadIdx.x;
  const int i0 = (int)blockIdx.x * 25;
  const int b  = (int)blockIdx.y;

  __shared__ float  att[2500];
  __shared__ uint32 att2[1250];
  __shared__ float  scratch[640];
  __shared__ float  rowmax[25], rowinv[25];

  const bool act = (t < 625);
  const int ti = act ? (t % 25) : 0;
  const int tj = act ? (t / 25) : 0;

  const uint32* Lrow = ws + LH_OFF + (size_t)(b*K_ + i0 + ti) * 100;
  const uint32* R0   = ws + RH_OFF + (size_t)(b*K_ + tj) * 100;
  const uint32* Ap   = ws + AH_OFF;

  float acc[4] = {0.f,0.f,0.f,0.f};
  float ar[4]  = {0.f,0.f,0.f,0.f};
  float al = 0.f;
  h2 z2; z2.x = (half_t)0; z2.y = (half_t)0;

  #pragma unroll
  for (int g = 0; g < 12; ++g) {
    const int ba = 8*g;
    uint4 La = *(const uint4*)(Lrow + ba),      Lb = *(const uint4*)(Lrow + ba + 4);
    uint4 Aa = *(const uint4*)(Ap + ba),        Ab = *(const uint4*)(Ap + ba + 4);
    uint4 R0a = *(const uint4*)(R0 + ba),       R0b = *(const uint4*)(R0 + ba + 4);
    uint4 R1a = *(const uint4*)(R0 + 2500+ba),  R1b = *(const uint4*)(R0 + 2500+ba+4);
    uint4 R2a = *(const uint4*)(R0 + 5000+ba),  R2b = *(const uint4*)(R0 + 5000+ba+4);
    uint4 R3a = *(const uint4*)(R0 + 7500+ba),  R3b = *(const uint4*)(R0 + 7500+ba+4);
    STEP(La.x, Aa.x, R0a.x, R1a.x, R2a.x, R3a.x);
    STEP(La.y, Aa.y, R0a.y, R1a.y, R2a.y, R3a.y);
    STEP(La.z, Aa.z, R0a.z, R1a.z, R2a.z, R3a.z);
    STEP(La.w, Aa.w, R0a.w, R1a.w, R2a.w, R3a.w);
    STEP(Lb.x, Ab.x, R0b.x, R1b.x, R2b.x, R3b.x);
    STEP(Lb.y, Ab.y, R0b.y, R1b.y, R2b.y, R3b.y);
    STEP(Lb.z, Ab.z, R0b.z, R1b.z, R2b.z, R3b.z);
    STEP(Lb.w, Ab.w, R0b.w, R1b.w, R2b.w, R3b.w);
  }
  {
    uint4 La = *(const uint4*)(Lrow + 96);
    uint4 Aa = *(const uint4*)(Ap + 96);
    uint4 R0a = *(const uint4*)(R0 + 96);
    uint4 R1a = *(const uint4*)(R0 + 2596);
    uint4 R2a = *(const uint4*)(R0 + 5096);
    uint4 R3a = *(const uint4*)(R0 + 7596);
    STEP(La.x, Aa.x, R0a.x, R1a.x, R2a.x, R3a.x);
    STEP(La.y, Aa.y, R0a.y, R1a.y, R2a.y, R3a.y);
    STEP(La.z, Aa.z, R0a.z, R1a.z, R2a.z, R3a.z);
    STEP(La.w, Aa.w, R0a.w, R1a.w, R2a.w, R3a.w);
  }

  float v[4];
  if (act) {
    #pragma unroll
    for (int s = 0; s < 4; ++s) {
      int j = tj + 25*s;
      float lv = al + ar[s] + bias[(i0 + ti)*K_ + j] - 0.8f*acc[s];
      v[s] = fminf(fmaxf(lv, -30000.f), 30000.f);
    }
  }

  {
    float m = -3.0e38f;
    if (act) {
      #pragma unroll
      for (int s = 0; s < 4; ++s) m = fmaxf(m, v[s]);
    }
    scratch[t] = m;
    __syncthreads();
    if (t < 25) {
      float mm = scratch[t];
      for (int k = 1; k < 25; ++k) mm = fmaxf(mm, scratch[t + 25*k]);
      rowmax[t] = mm;
    }
    __syncthreads();
    float ssum = 0.f;
    if (act) {
      float m2 = rowmax[ti];
      #pragma unroll
      for (int s = 0; s < 4; ++s) ssum += __expf(v[s] - m2);
    }
    scratch[t] = ssum;
    __syncthreads();
    if (t < 25) {
      float s2 = 0.f;
      for (int k = 0; k < 25; ++k) s2 += scratch[t + 25*k];
      rowinv[t] = 1.f / s2;
    }
    __syncthreads();
  }
  if (act) {
    float m = rowmax[ti], inv = rowinv[ti];
    #pragma unroll
    for (int s = 0; s < 4; ++s)
      att[ti*K_ + tj + 25*s] = __expf(v[s] - m) * inv;
  }
  __syncthreads();
  for (int u = t; u < 1250; u += 640) {
    int i = u / 50, jp = u - i*50;
    att2[i*50 + jp] = pkh2(att[i*K_ + 2*jp], att[i*K_ + 2*jp + 1]);
  }
  __syncthreads();

  {
    const int f = t & 127, ig = t >> 7;
    float z[5];
    #pragma unroll
    for (int m = 0; m < 5; ++m) z[m] = 0.f;
    const float* xb = x + (size_t)b*K_*F_ + f;
    for (int jp = 0; jp < 50; ++jp) {
      float x0 = xb[(size_t)(2*jp)*F_];
      float x1 = xb[(size_t)(2*jp+1)*F_];
      h2 xv = bch2(pkh2(x0, x1));
      #pragma unroll
      for (int m = 0; m < 5; ++m) {
        h2 av = bch2(att2[(ig + 5*m)*50 + jp]);
        z[m] = FDOT2(av, xv, z[m]);
      }
    }
    #pragma unroll
    for (int m = 0; m < 5; ++m) {
      int i = ig + 5*m;
      out[(size_t)(b*K_ + i0 + i)*F_ + f] = 1.f / (1.f + __expf(-z[m]));
    }
  }
}

extern "C" void kernel_launch(void* const* d_in, const int* in_sizes, int n_in,
                              void* d_out, int out_size, void* d_ws, size_t ws_size,
                              hipStream_t stream)
{
  const float* x    = (const float*)d_in[0];   // (64,100,128) f32
  const float* W    = (const float*)d_in[1];   // (256,200) f32
  const float* bvec = (const float*)d_in[2];   // (200,) f32
  const float* avec = (const float*)d_in[3];   // (200,) f32
  const float* bias = (const float*)d_in[4];   // (100,100) f32
  float* out  = (float*)d_out;                 // (64,100,128) f32
  uint32* ws  = (uint32*)d_ws;                 // ~5.2 MB used

  k_wt  <<<dim3(25),    dim3(256), 0, stream>>>(W, avec, ws);
  k_proj<<<dim3(640),   dim3(256), 0, stream>>>(x, bvec, ws);
  k_main<<<dim3(4, 64), dim3(640), 0, stream>>>(x, bias, ws, out);
}